// Round 9
// baseline (924.754 us; speedup 1.0000x reference)
//
#include <hip/hip_runtime.h>
#include <hip/hip_bf16.h>
#include <cstdint>

// LISTA: Z = eta(X@We^T + Z@S^T), 16 steps. B=16384, n=256, m=1024.
// Round-9 = round-8 resubmission (container infra failure, kernel never ran)
// with UB hygiene on the NTZ==0 instantiation. Design:
// A-OPERAND FROM GLOBAL TO REGISTERS (LDS holds B only).
// Diagnosis: rounds 2/4/6/7 all ~50us regardless of schedule -> binding
// resource is the shared LDS pipe (192 ds_read_b128/tile/CU ~ 2300cyc/tile
// > MFMA 2067). Fix: store A (X and Z) in MFMA-fragment-tiled layout
//   addr(r,k) = [kt=k>>6][mb=r>>5] * 4096 + ((k>>4)&3)*1024 + ((k>>3)&1)*512
//               + (r&31)*16 + (k&7)*2
// so af[mf][kk] is ONE fully-coalesced 1KB global_load_dwordx4 per wave
// (lane addr = l5*512 + r31*16, contiguous). Z is written tiled by the
// epilogue (slab transpose); X pre-tiled once by cvtX_tiled. B unchanged
// (LDS, swz2 swizzle, g2lds16). LDS reads drop 24->8 b128/tile/wave ->
// MFMA-bound. Per tile: 2 half-phases; afA(mh0)/afB(mh1) fixed sets loaded
// a half-tile ahead; B staged 1 tile ahead into the OPPOSITE buffer, issued
// only after a barrier that postdates all reads of that buffer. Race-free:
// each wave's STAGE_B(t) DMA is drained by its own mid-tile VM0 before the
// end-of-tile barrier -> all-wave visibility before any tile-t LOAD_B8.
// Waits: VM0 at each half-top (everything outstanding is needed now);
// WL4/WL0 split bf0/bf1. One barrier per tile. Math order identical to
// round 6 -> absmax must be exactly 0.15625.

typedef __attribute__((ext_vector_type(8))) short short8;    // 8 x bf16
typedef __attribute__((ext_vector_type(16))) float f32x16;   // 32x32 mfma acc

__device__ __forceinline__ void g2lds16(const void* g, void* l) {
    __builtin_amdgcn_global_load_lds(
        (const __attribute__((address_space(1))) uint32_t*)(uintptr_t)g,
        (__attribute__((address_space(3))) uint32_t*)(uintptr_t)l,
        16, 0, 0);
}

#define VM0  asm volatile("s_waitcnt vmcnt(0)" ::: "memory")
#define WL4  asm volatile("s_waitcnt lgkmcnt(4)" ::: "memory")
#define WL0  asm volatile("s_waitcnt lgkmcnt(0)" ::: "memory")
#define SGB  __builtin_amdgcn_sched_barrier(0)

// A-fragments (2 m-frags x 4 k-slices) for tile TT, m-half MH -> registers.
#define ISSUE_A(DST, TT, MH) do { \
    const char* ab_; \
    if constexpr (NTZ == 0) ab_ = AxB + (size_t)(TT) * KTS + (MH) * 8192; \
    else ab_ = (((TT) < NTX) ? AxB + (size_t)(TT) * KTS \
                             : AzB + (size_t)((TT) - NTX) * KTS) + (MH) * 8192; \
    _Pragma("unroll") \
    for (int mf_ = 0; mf_ < 2; ++mf_) \
    _Pragma("unroll") \
    for (int kk_ = 0; kk_ < 4; ++kk_) \
        DST[mf_][kk_] = *(const short8*)(ab_ + mf_ * 4096 + kk_ * 1024); \
} while (0)

// B-fragments: both col-halves of tile in buffer P (8 ds_read_b128).
#define LOAD_B8(P) do { \
    const char* bp_ = &lds[(P) * 32768] + brow; \
    bf0[0] = *(const short8*)(bp_ + ck0); \
    bf0[1] = *(const short8*)(bp_ + ck1); \
    bf0[2] = *(const short8*)(bp_ + ck2); \
    bf0[3] = *(const short8*)(bp_ + ck3); \
    bf1[0] = *(const short8*)(bp_ + 4096 + ck0); \
    bf1[1] = *(const short8*)(bp_ + 4096 + ck1); \
    bf1[2] = *(const short8*)(bp_ + 4096 + ck2); \
    bf1[3] = *(const short8*)(bp_ + 4096 + ck3); \
} while (0)

#define MFMA8(AF, MB, H, BF) do { \
    _Pragma("unroll") \
    for (int kk_ = 0; kk_ < 4; ++kk_) \
    _Pragma("unroll") \
    for (int mf_ = 0; mf_ < 2; ++mf_) \
        acc[(MB) + mf_][H] = __builtin_amdgcn_mfma_f32_32x32x16_bf16( \
            AF[mf_][kk_], BF[kk_], acc[(MB) + mf_][H], 0, 0, 0); \
} while (0)

// One K-tile (two half-phases), single barrier at end.
#define TILE(TT, DO_NEXT) do { \
    VM0; SGB; \
    if (DO_NEXT) STAGE_B((TT) + 1); \
    ISSUE_A(afB, (TT), 1); \
    LOAD_B8((TT) & 1); \
    WL4; SGB; \
    __builtin_amdgcn_s_setprio(1); \
    MFMA8(afA, 0, 0, bf0); \
    WL0; SGB; \
    MFMA8(afA, 0, 1, bf1); \
    __builtin_amdgcn_s_setprio(0); \
    VM0; SGB; \
    if (DO_NEXT) ISSUE_A(afA, (TT) + 1, 0); \
    __builtin_amdgcn_s_setprio(1); \
    MFMA8(afB, 2, 0, bf0); \
    MFMA8(afB, 2, 1, bf1); \
    __builtin_amdgcn_s_setprio(0); \
    __builtin_amdgcn_s_barrier(); SGB; \
} while (0)

// A-tiles 0..NTX-1 from Axt (X tiled), NTX.. from Azt (Z tiled); B row-major.
template<int NTX, int NTZ, bool LAST>
__global__ void __launch_bounds__(512, 2)
lista_step(const unsigned short* __restrict__ Axt,
           const unsigned short* __restrict__ Wx,
           const unsigned short* __restrict__ Azt,
           const unsigned short* __restrict__ Wz,
           const float* __restrict__ theta,
           unsigned short* __restrict__ Zout,   // tiled layout (unless LAST)
           float* __restrict__ Fout)
{
    constexpr int NT  = NTX + NTZ;
    constexpr int KBX = NTX * 128;           // We row stride (bytes)
    constexpr int KBZ = (NTZ ? NTZ : 1) * 128;  // S row stride (bytes)
    constexpr size_t KTS = (size_t)512 * 4096;  // A k-tile stride (2 MB)

    // [0,64K): B double buffer (2 x 256 rows x 128 B); full 128K: epi slabs.
    __shared__ __align__(128) char lds[131072];

    const int tid  = threadIdx.x;            // 0..511
    const int lane = tid & 63;
    const int wave = tid >> 6;               // 0..7
    const int wm   = wave >> 2;              // 0..1
    const int wn   = wave & 3;               // 0..3
    const int bm   = blockIdx.x;             // 0..63
    const int bn   = blockIdx.y;             // 0..3

    // ---- B staging: chunk I = c*512+tid (c=0..3), row u=I>>3, slot=I&7;
    // slot holds global k-chunk slot ^ swz2(u), swz2(r)=(r^(r>>2))&7 (bits0-4).
    const int u0   = tid >> 3;               // row for c=0; +64 per c
    const int gb16 = ((tid & 7) ^ (((u0 & 31) ^ ((u0 & 31) >> 2)) & 7)) << 4;

    // ---- fragment constants
    const int r31 = lane & 31;
    const int l5  = lane >> 5;
    const int sw  = (r31 ^ (r31 >> 2)) & 7;
    const int ck0 = ((0 + l5) ^ sw) << 4;
    const int ck1 = ((2 + l5) ^ sw) << 4;
    const int ck2 = ((4 + l5) ^ sw) << 4;
    const int ck3 = ((6 + l5) ^ sw) << 4;
    const int brow = (wn * 64 + r31) * 128;  // bf1 adds +32 rows = +4096

    // ---- A bases (fragment-tiled): per-lane offset l5*512 + r31*16
    const size_t mboff = (size_t)(bm * 8 + wm * 4) * 4096 + l5 * 512 + r31 * 16;
    const char* AxB = (const char*)Axt + mboff;
    const char* AzB = (NTZ ? (const char*)Azt + mboff : (const char*)nullptr);

    const char* WxB = (const char*)Wx + (size_t)bn * 256 * KBX;
    const char* WzB = (NTZ ? (const char*)Wz + (size_t)bn * 256 * KBZ
                           : (const char*)nullptr);

    auto STAGE_B = [&](int kt) {
        const char* base; int kb, ko;
        if (NTZ == 0 || kt < NTX) { base = WxB; kb = KBX; ko = kt * 128; }
        else                      { base = WzB; kb = KBZ; ko = (kt - NTX) * 128; }
        char* lp = &lds[(kt & 1) * 32768] + tid * 16;
        const size_t go = (size_t)u0 * kb + ko + gb16;
        const size_t rs = (size_t)64 * kb;
        g2lds16(base + go,          lp);
        g2lds16(base + go + rs,     lp + 8192);
        g2lds16(base + go + 2 * rs, lp + 16384);
        g2lds16(base + go + 3 * rs, lp + 24576);
    };

    f32x16 acc[4][2];
#pragma unroll
    for (int i = 0; i < 4; ++i)
#pragma unroll
        for (int j = 0; j < 2; ++j)
#pragma unroll
            for (int r = 0; r < 16; ++r) acc[i][j][r] = 0.f;

    short8 afA[2][4], afB[2][4], bf0[4], bf1[4];

    // prologue: B(0) + afA(0,mh0); drain; barrier (cross-wave B visibility).
    STAGE_B(0);
    ISSUE_A(afA, 0, 0);
    VM0;
    __builtin_amdgcn_s_barrier(); SGB;

    // main loop: tile t reads B-buf t&1; stages B(t+1) -> buf (t+1)&1 at top
    // (that buf's previous reads all pre-date the last barrier); A half-tile
    // prefetch into the idle named set. VM0 at half-tops drains exactly the
    // operands needed next (nothing long-lived outstanding).
#pragma unroll 1
    for (int t = 0; t < NT - 1; ++t) TILE(t, true);
    TILE(NT - 1, false);

    // ---- epilogue. C/D: col=lane&31, row=(reg&3)+8*(reg>>2)+4*l5.
    const int colb = bn * 256 + wn * 64 + r31;
    const float th0 = theta[colb];
    const float th1 = theta[colb + 32];

    if constexpr (LAST) {
        const int rowb = bm * 256 + wm * 128;
#pragma unroll
        for (int MF = 0; MF < 4; ++MF)
#pragma unroll
        for (int reg = 0; reg < 16; ++reg) {
            const int rrow = rowb + MF * 32 + (reg & 3) + 8 * (reg >> 2) + 4 * l5;
#pragma unroll
            for (int h = 0; h < 2; ++h) {
                const float c = acc[MF][h][reg];
                const float a = fabsf(c) - (h ? th1 : th0);
                const float z = a > 0.f ? (c > 0.f ? a : -a) : 0.f;
                Fout[(size_t)rrow * 1024 + colb + h * 32] = z;
            }
        }
    } else {
        // slab transpose (per-wave 16KB, swizzled), then FRAGMENT-TILED store:
        // wave's 128x64 block = k-tile kt'=bn*4+wn, m-blocks bm*8+wm*4+MF.
        char* slab = &lds[wave * 16384];
#pragma unroll
        for (int MF = 0; MF < 4; ++MF)
#pragma unroll
        for (int h = 0; h < 2; ++h)
#pragma unroll
        for (int reg = 0; reg < 16; ++reg) {
            const int row = MF * 32 + (reg & 3) + 8 * (reg >> 2) + 4 * l5;
            const int cb  = (h * 64 + r31 * 2) ^ ((row & 7) << 4);
            const float c = acc[MF][h][reg];
            const float a = fabsf(c) - (h ? th1 : th0);
            const float z = a > 0.f ? (c > 0.f ? a : -a) : 0.f;
            __hip_bfloat16 hb = __float2bfloat16(z);
            *(unsigned short*)(slab + row * 128 + cb) = *(const unsigned short*)&hb;
        }
        SGB;
        char* zb = (char*)Zout + (size_t)(bn * 4 + wn) * KTS
                 + (size_t)(bm * 8 + wm * 4) * 4096;
#pragma unroll
        for (int MF = 0; MF < 4; ++MF)
#pragma unroll
        for (int kk = 0; kk < 4; ++kk) {
            const int srow  = MF * 32 + r31;
            const int sbyte = (kk * 32 + l5 * 16) ^ ((srow & 7) << 4);
            const short8 v = *(const short8*)(slab + srow * 128 + sbyte);
            *(short8*)(zb + MF * 4096 + kk * 1024 + l5 * 512 + r31 * 16) = v;
        }
    }
}

__global__ void __launch_bounds__(256)
cvt4(const float* __restrict__ s, unsigned short* __restrict__ d, int n4)
{
    const int i = blockIdx.x * blockDim.x + threadIdx.x;
    if (i < n4) {
        const float4 v = ((const float4*)s)[i];
        ushort4 o;
        __hip_bfloat16 b;
        b = __float2bfloat16(v.x); o.x = *(unsigned short*)&b;
        b = __float2bfloat16(v.y); o.y = *(unsigned short*)&b;
        b = __float2bfloat16(v.z); o.z = *(unsigned short*)&b;
        b = __float2bfloat16(v.w); o.w = *(unsigned short*)&b;
        ((ushort4*)d)[i] = o;
    }
}

// X (16384x256 fp32 row-major) -> bf16 fragment-tiled [kt][mb][kk][l5][r31][8]
__global__ void __launch_bounds__(256)
cvtX_tiled(const float* __restrict__ X, unsigned short* __restrict__ Xt)
{
    const int gid = blockIdx.x * 256 + threadIdx.x;   // 0..524287 (16B chunks)
    const int kt  = gid >> 17;           // 131072 chunks per k-tile
    const int mb  = (gid >> 8) & 511;
    const int q   = gid & 255;           // (kk*2+l5)*32 + r31
    const int r   = q & 31;
    const int kk  = q >> 6;
    const int l5q = (q >> 5) & 1;
    const int row = mb * 32 + r;
    const int k0  = kt * 64 + kk * 16 + l5q * 8;
    const float4 a = *(const float4*)(X + (size_t)row * 256 + k0);
    const float4 b = *(const float4*)(X + (size_t)row * 256 + k0 + 4);
    unsigned short o[8];
    __hip_bfloat16 hb;
    hb = __float2bfloat16(a.x); o[0] = *(unsigned short*)&hb;
    hb = __float2bfloat16(a.y); o[1] = *(unsigned short*)&hb;
    hb = __float2bfloat16(a.z); o[2] = *(unsigned short*)&hb;
    hb = __float2bfloat16(a.w); o[3] = *(unsigned short*)&hb;
    hb = __float2bfloat16(b.x); o[4] = *(unsigned short*)&hb;
    hb = __float2bfloat16(b.y); o[5] = *(unsigned short*)&hb;
    hb = __float2bfloat16(b.z); o[6] = *(unsigned short*)&hb;
    hb = __float2bfloat16(b.w); o[7] = *(unsigned short*)&hb;
    *(short8*)(Xt + (size_t)gid * 8) = *(const short8*)o;
}

extern "C" void kernel_launch(void* const* d_in, const int* in_sizes, int n_in,
                              void* d_out, int out_size, void* d_ws, size_t ws_size,
                              hipStream_t stream) {
    (void)in_sizes; (void)n_in; (void)out_size; (void)ws_size;
    const float* X     = (const float*)d_in[0];  // 16384 x 256
    const float* We    = (const float*)d_in[1];  // 1024 x 256
    const float* S     = (const float*)d_in[2];  // 1024 x 1024
    const float* theta = (const float*)d_in[3];  // 1024
    float* out = (float*)d_out;                  // 16384 x 1024 fp32

    char* ws = (char*)d_ws;
    unsigned short* S_bf  = (unsigned short*)(ws);                           //  2 MB
    unsigned short* X_t   = (unsigned short*)(ws + (size_t)2  * 1048576);    //  8 MB (tiled)
    unsigned short* We_bf = (unsigned short*)(ws + (size_t)10 * 1048576);    // 0.5 MB
    unsigned short* Za    = (unsigned short*)(ws + (size_t)11 * 1048576);    // 32 MB (tiled)
    unsigned short* Zb    = (unsigned short*)(ws + (size_t)43 * 1048576);    // 32 MB (tiled)

    cvt4<<<dim3(1024), dim3(256), 0, stream>>>(S,  S_bf,  1024 * 1024 / 4);
    cvt4<<<dim3(256),  dim3(256), 0, stream>>>(We, We_bf, 1024 * 256 / 4);
    cvtX_tiled<<<dim3(2048), dim3(256), 0, stream>>>(X, X_t);

    const dim3 grid(64, 4), blk(512);

    // Z0 = eta(X @ We^T)            (K = 256)
    lista_step<4, 0, false><<<grid, blk, 0, stream>>>(
        X_t, We_bf, nullptr, nullptr, theta, Za, nullptr);

    // steps 1..15: Z = eta([X,Z] @ [We,S]^T)   (K = 1280), ping-pong tiled bf16
    unsigned short* zin = Za;
    unsigned short* zout = Zb;
    for (int tstep = 1; tstep <= 15; ++tstep) {
        lista_step<4, 16, false><<<grid, blk, 0, stream>>>(
            X_t, We_bf, zin, S_bf, theta, zout, nullptr);
        unsigned short* tmp = zin; zin = zout; zout = tmp;
    }
    // step 16: write fp32 output directly
    lista_step<4, 16, true><<<grid, blk, 0, stream>>>(
        X_t, We_bf, zin, S_bf, theta, nullptr, out);
}

// Round 10
// 873.380 us; speedup vs baseline: 1.0588x; 1.0588x over previous
//
#include <hip/hip_runtime.h>
#include <hip/hip_bf16.h>
#include <cstdint>

// LISTA: Z = eta(X@We^T + Z@S^T), 16 steps. B=16384, n=256, m=1024.
// Round-10: TWO BLOCKS PER CU, simple schedule (inter-block overlap).
// History: rounds 2/4/6/7 (1 block/CU, 8 waves, every intra-block schedule)
// all ~48.6us middles; round 9 (A via L1) 59.9. MFMA floor 17.2us, operand
// traffic ~19us on LDS -> the missing ~29us is sync serialization that
// intra-block scheduling cannot remove at 2 waves/SIMD lockstep. Mechanism
// not yet tried: independent co-resident blocks (m114/m97: implicit overlap,
// 874 TF with no explicit pipelining at >=2 blocks/CU).
// Geometry: BM=256 x BN=128, 4 waves (2Mx2N), wave-tile 128x64 (same per-wave
// cost as round 6: 24 ds_read_b128 + 32 mfma_32x32x16 per K-tile), BK=64,
// SINGLE-buffered LDS 48KB (A 32K + B 16K; 64K alloc for epilogue slabs),
// grid 64x8=512 = 2 blocks/CU, __launch_bounds__(256,2). swz2 chunk swizzle
// on both stage + read sides (proven conflict-free). Two __syncthreads per
// K-tile; compiler inserts vmcnt/lgkm waits (m97 philosophy). Fused
// C = [X,Z] @ [We,S]^T (K=1280, NT=20); Z row-major bf16 ping-pong; slab-
// transposed bf16 epilogue (full 128B-line stores); fp32 direct on LAST.
// absmax canary: math order identical to rounds 1-6 -> expect exactly 0.15625.

typedef __attribute__((ext_vector_type(8))) short short8;    // 8 x bf16
typedef __attribute__((ext_vector_type(16))) float f32x16;   // 32x32 mfma acc

__device__ __forceinline__ void g2lds16(const void* g, void* l) {
    __builtin_amdgcn_global_load_lds(
        (const __attribute__((address_space(1))) uint32_t*)(uintptr_t)g,
        (__attribute__((address_space(3))) uint32_t*)(uintptr_t)l,
        16, 0, 0);
}

// A-tiles 0..NTX-1 from Ax (X bf16 row-major), NTX.. from Az (Z bf16 row-major).
// B rows (output cols) from Wx (We) / Wz (S), bf16 row-major.
template<int NTX, int NTZ, bool LAST>
__global__ void __launch_bounds__(256, 2)
lista_step(const unsigned short* __restrict__ Ax,
           const unsigned short* __restrict__ Wx,
           const unsigned short* __restrict__ Az,
           const unsigned short* __restrict__ Wz,
           const float* __restrict__ theta,
           unsigned short* __restrict__ Zout,
           float* __restrict__ Fout)
{
    constexpr int NT  = NTX + NTZ;
    constexpr int KBX = NTX * 128;              // X/We row stride (bytes)
    constexpr int KBZ = (NTZ ? NTZ : 1) * 128;  // Z/S  row stride (bytes)

    // [0,32K): A tile (256 rows x 128B). [32K,48K): B tile (128 rows x 128B).
    // Epilogue reuses all 64K as 4 x 16K per-wave slabs.
    __shared__ __align__(128) char lds[65536];
    char* const Ash = lds;
    char* const Bsh = lds + 32768;

    const int tid  = threadIdx.x;      // 0..255
    const int lane = tid & 63;
    const int wave = tid >> 6;         // 0..3
    const int wm   = wave >> 1;        // 0..1 (M half: 128 rows)
    const int wn   = wave & 1;         // 0..1 (N half: 64 cols)
    const int bm   = blockIdx.x;       // 0..63
    const int bn   = blockIdx.y;       // 0..7

    // ---- staging constants: call c handles chunk I = c*256+tid ->
    // row = c*32 + u, slot = tid&7; slot holds global k-chunk slot^swz2(u),
    // swz2(r) = (r ^ (r>>2)) & 7 (row bits 0-4; row%32 == u for all c).
    const int u    = tid >> 3;                       // 0..31
    const int gb16 = ((tid & 7) ^ ((u ^ (u >> 2)) & 7)) << 4;

    // ---- fragment-read constants (32x32x16: row=lane&31, k=(lane>>5)*8+e)
    const int r31 = lane & 31;
    const int l5  = lane >> 5;
    const int sw  = (r31 ^ (r31 >> 2)) & 7;
    const int ck0 = ((0 + l5) ^ sw) << 4;
    const int ck1 = ((2 + l5) ^ sw) << 4;
    const int ck2 = ((4 + l5) ^ sw) << 4;
    const int ck3 = ((6 + l5) ^ sw) << 4;
    const int arow = (wm * 128 + r31) * 128;   // + mf*4096 for mf=0..3
    const int brow = (wn * 64 + r31) * 128;    // + nf*4096 for nf=0..1

    const char* AxB = (const char*)Ax + (size_t)(bm * 256) * KBX;
    const char* AzB = (NTZ ? (const char*)Az + (size_t)(bm * 256) * KBZ
                           : (const char*)nullptr);
    const char* WxB = (const char*)Wx + (size_t)(bn * 128) * KBX;
    const char* WzB = (NTZ ? (const char*)Wz + (size_t)(bn * 128) * KBZ
                           : (const char*)nullptr);

    f32x16 acc[4][2];
#pragma unroll
    for (int i = 0; i < 4; ++i)
#pragma unroll
        for (int j = 0; j < 2; ++j)
#pragma unroll
            for (int r = 0; r < 16; ++r) acc[i][j][r] = 0.f;

    // ---- main loop: single-buffered, 2 barriers/tile, no explicit waitcnt.
    // Overlap comes from the co-resident second block on the CU.
#pragma unroll 1
    for (int kt = 0; kt < NT; ++kt) {
        __syncthreads();   // tile kt-1 LDS reads complete (all waves)
        {
            const char* ab; int kba, koa;
            if (NTZ == 0 || kt < NTX) { ab = AxB; kba = KBX; koa = kt * 128; }
            else                      { ab = AzB; kba = KBZ; koa = (kt - NTX) * 128; }
#pragma unroll
            for (int c = 0; c < 8; ++c)
                g2lds16(ab + (size_t)(c * 32 + u) * kba + koa + gb16,
                        Ash + c * 4096 + tid * 16);
            const char* bb; int kbb, kob;
            if (NTZ == 0 || kt < NTX) { bb = WxB; kbb = KBX; kob = kt * 128; }
            else                      { bb = WzB; kbb = KBZ; kob = (kt - NTX) * 128; }
#pragma unroll
            for (int c = 0; c < 4; ++c)
                g2lds16(bb + (size_t)(c * 32 + u) * kbb + kob + gb16,
                        Bsh + c * 4096 + tid * 16);
        }
        __syncthreads();   // staged data visible (vmcnt(0) at barrier)

#pragma unroll
        for (int kk = 0; kk < 4; ++kk) {
            const int ck = (kk == 0) ? ck0 : (kk == 1) ? ck1 : (kk == 2) ? ck2 : ck3;
            const char* ap = Ash + arow + ck;
            const char* bp = Bsh + brow + ck;
            const short8 a0 = *(const short8*)(ap);
            const short8 a1 = *(const short8*)(ap + 4096);
            const short8 a2 = *(const short8*)(ap + 8192);
            const short8 a3 = *(const short8*)(ap + 12288);
            const short8 b0 = *(const short8*)(bp);
            const short8 b1 = *(const short8*)(bp + 4096);
            acc[0][0] = __builtin_amdgcn_mfma_f32_32x32x16_bf16(a0, b0, acc[0][0], 0, 0, 0);
            acc[1][0] = __builtin_amdgcn_mfma_f32_32x32x16_bf16(a1, b0, acc[1][0], 0, 0, 0);
            acc[2][0] = __builtin_amdgcn_mfma_f32_32x32x16_bf16(a2, b0, acc[2][0], 0, 0, 0);
            acc[3][0] = __builtin_amdgcn_mfma_f32_32x32x16_bf16(a3, b0, acc[3][0], 0, 0, 0);
            acc[0][1] = __builtin_amdgcn_mfma_f32_32x32x16_bf16(a0, b1, acc[0][1], 0, 0, 0);
            acc[1][1] = __builtin_amdgcn_mfma_f32_32x32x16_bf16(a1, b1, acc[1][1], 0, 0, 0);
            acc[2][1] = __builtin_amdgcn_mfma_f32_32x32x16_bf16(a2, b1, acc[2][1], 0, 0, 0);
            acc[3][1] = __builtin_amdgcn_mfma_f32_32x32x16_bf16(a3, b1, acc[3][1], 0, 0, 0);
        }
    }

    // ---- epilogue. C/D: col = lane&31, row = (reg&3)+8*(reg>>2)+4*l5.
    const int colb = bn * 128 + wn * 64 + r31;
    const float th0 = theta[colb];
    const float th1 = theta[colb + 32];
    const int rowb = bm * 256 + wm * 128;

    if constexpr (LAST) {
        // fp32 direct: 32 lanes x 4B = full 128B line per row-chunk.
#pragma unroll
        for (int MF = 0; MF < 4; ++MF)
#pragma unroll
        for (int reg = 0; reg < 16; ++reg) {
            const int rrow = rowb + MF * 32 + (reg & 3) + 8 * (reg >> 2) + 4 * l5;
#pragma unroll
            for (int h = 0; h < 2; ++h) {
                const float c = acc[MF][h][reg];
                const float a = fabsf(c) - (h ? th1 : th0);
                const float z = a > 0.f ? (c > 0.f ? a : -a) : 0.f;
                Fout[(size_t)rrow * 1024 + colb + h * 32] = z;
            }
        }
    } else {
        // bf16 via per-wave 16KB LDS transpose slab; readback row-linear ->
        // each global store = 8 rows x full 128B lines (no write RMW).
        __syncthreads();   // main-loop LDS reads done before slab overwrite
        char* slab = &lds[wave * 16384];
#pragma unroll
        for (int MF = 0; MF < 4; ++MF)
#pragma unroll
        for (int h = 0; h < 2; ++h)
#pragma unroll
        for (int reg = 0; reg < 16; ++reg) {
            const int row = MF * 32 + (reg & 3) + 8 * (reg >> 2) + 4 * l5;
            const int cb  = (h * 64 + r31 * 2) ^ ((row & 7) << 4);
            const float c = acc[MF][h][reg];
            const float a = fabsf(c) - (h ? th1 : th0);
            const float z = a > 0.f ? (c > 0.f ? a : -a) : 0.f;
            __hip_bfloat16 hb = __float2bfloat16(z);
            *(unsigned short*)(slab + row * 128 + cb) = *(const unsigned short*)&hb;
        }
        __builtin_amdgcn_sched_barrier(0);
#pragma unroll
        for (int i = 0; i < 16; ++i) {
            const int r = i * 8 + (lane >> 3);
            const short8 v = *(const short8*)(slab + r * 128 + (((lane & 7) ^ (r & 7)) << 4));
            char* gp = (char*)Zout + (size_t)(rowb + r) * 2048
                     + bn * 256 + wn * 128 + (lane & 7) * 16;
            *(short8*)gp = v;
        }
    }
}

__global__ void __launch_bounds__(256)
cvt4(const float* __restrict__ s, unsigned short* __restrict__ d, int n4)
{
    const int i = blockIdx.x * blockDim.x + threadIdx.x;
    if (i < n4) {
        const float4 v = ((const float4*)s)[i];
        ushort4 o;
        __hip_bfloat16 b;
        b = __float2bfloat16(v.x); o.x = *(unsigned short*)&b;
        b = __float2bfloat16(v.y); o.y = *(unsigned short*)&b;
        b = __float2bfloat16(v.z); o.z = *(unsigned short*)&b;
        b = __float2bfloat16(v.w); o.w = *(unsigned short*)&b;
        ((ushort4*)d)[i] = o;
    }
}

extern "C" void kernel_launch(void* const* d_in, const int* in_sizes, int n_in,
                              void* d_out, int out_size, void* d_ws, size_t ws_size,
                              hipStream_t stream) {
    (void)in_sizes; (void)n_in; (void)out_size; (void)ws_size;
    const float* X     = (const float*)d_in[0];  // 16384 x 256
    const float* We    = (const float*)d_in[1];  // 1024 x 256
    const float* S     = (const float*)d_in[2];  // 1024 x 1024
    const float* theta = (const float*)d_in[3];  // 1024
    float* out = (float*)d_out;                  // 16384 x 1024 fp32

    char* ws = (char*)d_ws;
    unsigned short* S_bf  = (unsigned short*)(ws);                           //  2 MB
    unsigned short* X_bf  = (unsigned short*)(ws + (size_t)2  * 1048576);    //  8 MB
    unsigned short* We_bf = (unsigned short*)(ws + (size_t)10 * 1048576);    // 0.5 MB
    unsigned short* Za    = (unsigned short*)(ws + (size_t)11 * 1048576);    // 32 MB
    unsigned short* Zb    = (unsigned short*)(ws + (size_t)43 * 1048576);    // 32 MB (total 75 MB)

    cvt4<<<dim3(1024), dim3(256), 0, stream>>>(S,  S_bf,  1024 * 1024 / 4);
    cvt4<<<dim3(4096), dim3(256), 0, stream>>>(X,  X_bf,  16384 * 256 / 4);
    cvt4<<<dim3(256),  dim3(256), 0, stream>>>(We, We_bf, 1024 * 256 / 4);

    const dim3 grid(64, 8), blk(256);   // 512 blocks = 2 per CU

    // Z0 = eta(X @ We^T)            (K = 256)
    lista_step<4, 0, false><<<grid, blk, 0, stream>>>(
        X_bf, We_bf, nullptr, nullptr, theta, Za, nullptr);

    // steps 1..15: Z = eta([X,Z] @ [We,S]^T)   (K = 1280), ping-pong bf16
    unsigned short* zin = Za;
    unsigned short* zout = Zb;
    for (int tstep = 1; tstep <= 15; ++tstep) {
        lista_step<4, 16, false><<<grid, blk, 0, stream>>>(
            X_bf, We_bf, zin, S_bf, theta, zout, nullptr);
        unsigned short* tmp = zin; zin = zout; zout = tmp;
    }
    // step 16: write fp32 output directly
    lista_step<4, 16, true><<<grid, blk, 0, stream>>>(
        X_bf, We_bf, zin, S_bf, theta, nullptr, out);
}